// Round 2
// 121.336 us; speedup vs baseline: 1.0234x; 1.0234x over previous
//
#include <hip/hip_runtime.h>

#define BB 4
#define NN 4096        // 64*64 spatial
#define CQK 64
#define DQ 16
#define CV 128

typedef __attribute__((ext_vector_type(8))) short bf16x8;
typedef __attribute__((ext_vector_type(4))) float f32x4;
typedef __attribute__((ext_vector_type(16))) float f32x16;
typedef __attribute__((ext_vector_type(8))) unsigned short u16x8;
typedef __attribute__((ext_vector_type(4))) unsigned int u32x4;

__device__ __forceinline__ unsigned short f2bf(float f) {
    unsigned int u = __builtin_bit_cast(unsigned int, f);
    u += 0x7FFFu + ((u >> 16) & 1u);   // RNE
    return (unsigned short)(u >> 16);
}
// truncation-pack two fp32 -> packed bf16x2 (v_perm_b32-foldable)
__device__ __forceinline__ unsigned int pk_trunc(float lo, float hi) {
    unsigned int a = __builtin_bit_cast(unsigned int, lo);
    unsigned int b = __builtin_bit_cast(unsigned int, hi);
    return (a >> 16) | (b & 0xFFFF0000u);
}

// ================= fused projections =================
// blocks 0..63:    Q/K projection (256 positions per block) -- FIRST so they
//                  overlap the V blocks instead of trailing as a tail.
// blocks 64..575:  V projection (2 blocks per 64-pos tile, 64 out-chans each)
__global__ __launch_bounds__(256, 4) void proj(
    const float* __restrict__ x,   // [B][64][N]
    const float* __restrict__ Wq, const float* __restrict__ bq,
    const float* __restrict__ Wk, const float* __restrict__ bk,
    const float* __restrict__ xh,  // [B][128][N]
    const float* __restrict__ Wv, const float* __restrict__ bv,
    unsigned short* __restrict__ qT, unsigned short* __restrict__ kT,
    unsigned short* __restrict__ vB)
{
    __shared__ __align__(16) float smem[8448];
    int tid = threadIdx.x;
    if (blockIdx.x >= 64) {
        // ---------- V projection ----------
        float* wvT = smem;            // [64 ci][66]
        float* xs  = smem + 4224;     // [64 ci][64 pos]
        float* bvs = smem + 8320;     // [64]
        int bid = blockIdx.x - 64;
        int pt = bid >> 1, h = bid & 1;
        int i0 = pt * 64;
        int b = i0 >> 12, ib = i0 & 4095;
        int co0 = h * 64;
        if (tid < 64) bvs[tid] = bv[co0 + tid];
        int cog = tid & 31, ig = tid >> 5;   // 2 out-chans, 8 positions
        float acc[8][2];
#pragma unroll
        for (int q = 0; q < 8; q++) { acc[q][0] = 0.f; acc[q][1] = 0.f; }

        for (int ch = 0; ch < 2; ch++) {
            for (int t = tid; t < 4096; t += 256) {
                int c = t & 63, col = t >> 6;
                wvT[c * 66 + col] = Wv[(size_t)(co0 + col) * CV + ch * 64 + c];
            }
            for (int t = tid; t < 4096; t += 256) {
                int il = t & 63, c = t >> 6;
                xs[c * 64 + il] = xh[((size_t)b * CV + ch * 64 + c) * NN + ib + il];
            }
            __syncthreads();
            for (int c = 0; c < 64; c++) {
                float2 w2 = *(const float2*)&wvT[c * 66 + cog * 2];
                float4 xa = *(const float4*)&xs[c * 64 + ig * 8];
                float4 xb = *(const float4*)&xs[c * 64 + ig * 8 + 4];
                float xv[8] = { xa.x, xa.y, xa.z, xa.w, xb.x, xb.y, xb.z, xb.w };
#pragma unroll
                for (int q = 0; q < 8; q++) {
                    acc[q][0] += xv[q] * w2.x;
                    acc[q][1] += xv[q] * w2.y;
                }
            }
            __syncthreads();
        }
        // swizzled store: vB per 64-key tile holds 16 A-frags for
        // v_mfma_f32_32x32x16_bf16 (A = V, m=channel, k=key-in-chunk):
        //   frag i = g*4 + kchunk   (g = chan group of 32, kchunk = key/16)
        //   lane   = (co&31) + 32*((key>>3)&1)   (A: m=lane&31, k=8*(lane>>5)+j)
        //   elem j = key & 7
        int kt = ib >> 6;
        int hb = ig & 1, kc = ig >> 1;   // keys ig*8..ig*8+7 -> chunk kc, half hb
#pragma unroll
        for (int cc = 0; cc < 2; cc++) {
            int co = co0 + cog * 2 + cc;
            int g = co >> 5, cl = co & 31;
            float bb = bvs[cog * 2 + cc];
            u16x8 o;
#pragma unroll
            for (int jj = 0; jj < 8; jj++) o[jj] = f2bf(acc[jj][cc] + bb);
            size_t base = ((size_t)(b * 64 + kt)) * 8192
                        + (size_t)(((g * 4 + kc) * 64 + hb * 32 + cl)) * 8;
            *(u16x8*)(vB + base) = o;
        }
    } else {
        // ---------- Q/K projection ----------
        float* wqT = smem;          // [64 c][16 d]
        float* wkT = smem + 1024;
        float* bqs = smem + 2048;
        float* bks = smem + 2064;
        for (int t = tid; t < 1024; t += 256) {
            int c = t & 63, d = t >> 6;          // coalesced global read
            wqT[c * 16 + d] = Wq[d * CQK + c];
            wkT[c * 16 + d] = Wk[d * CQK + c];
        }
        if (tid < DQ) { bqs[tid] = bq[tid]; bks[tid] = bk[tid]; }
        __syncthreads();

        int gidx = blockIdx.x * 256 + tid;   // over B*N
        int b = gidx >> 12, i = gidx & 4095;
        float qa[DQ], ka[DQ];
#pragma unroll
        for (int d = 0; d < DQ; d++) { qa[d] = bqs[d]; ka[d] = bks[d]; }
        const float* xp = x + (size_t)b * CQK * NN + i;
        for (int c = 0; c < CQK; c++) {
            float xv = xp[(size_t)c * NN];
            const float4* wq4 = (const float4*)&wqT[c * DQ];
            const float4* wk4 = (const float4*)&wkT[c * DQ];
#pragma unroll
            for (int dd = 0; dd < 4; dd++) {
                float4 a = wq4[dd], e = wk4[dd];
                qa[dd*4+0] += a.x * xv; qa[dd*4+1] += a.y * xv;
                qa[dd*4+2] += a.z * xv; qa[dd*4+3] += a.w * xv;
                ka[dd*4+0] += e.x * xv; ka[dd*4+1] += e.y * xv;
                ka[dd*4+2] += e.z * xv; ka[dd*4+3] += e.w * xv;
            }
        }
        u16x8 q0, q1, k0, k1;
#pragma unroll
        for (int dd = 0; dd < 8; dd++) {
            q0[dd] = f2bf(qa[dd]);     q1[dd] = f2bf(qa[8 + dd]);
            k0[dd] = f2bf(ka[dd]);     k1[dd] = f2bf(ka[8 + dd]);
        }
        u16x8* qo = (u16x8*)(qT + (size_t)gidx * DQ);
        u16x8* ko = (u16x8*)(kT + (size_t)gidx * DQ);
        qo[0] = q0; qo[1] = q1;
        ko[0] = k0; ko[1] = k1;
    }
}

// ================= MFMA flash attention, 32 queries/block =================
// block = one 32-query group; wave w owns key tiles w*16..w*16+15 (split-K).
// QK^T via v_mfma_f32_32x32x16_bf16 (K=16 exact): S^T = K·Q^T,
// C: col=lane&31=q, row=key=(reg&3)+8*(reg>>2)+4*(lane>>5).
// PV via 4x v_mfma_f32_32x32x16_bf16 per 16-key chunk: A = V (m=chan group
// of 32, k=key-in-chunk), B = P (n=q). The P B-frag is built IN REGISTERS
// from the QK^T C-layout: per chunk 4x pk_trunc + 2x v_permlane32_swap_b32.
// HW semantics (confirmed by R1 failure): vdst.hi32lanes <-> vsrc.lo32lanes.
// So swap(D=A0,S=A2) yields A0={A0.lo|A2.lo}=word0, A2={A0.hi|A2.hi}=word2.
// (R1 had D/S reversed -> permuted softmax keys -> absmax 0.66.)
// This removes the old per-tile pT LDS round-trip that stalled MFMA at ~20%.
// (256,2): do NOT raise min-waves (R7 spill lesson). 32q/block optimum (R11).
__global__ __launch_bounds__(256, 2) void flash_mfma(
    const unsigned short* __restrict__ qTb,  // [B*N][16] bf16
    const unsigned short* __restrict__ kTb,  // [B*N][16] bf16
    const unsigned short* __restrict__ vB,   // swizzled bf16 (32x32 A-frag order)
    const float* __restrict__ xh,            // [B][128][N]
    const float* __restrict__ gamma,
    float* __restrict__ out)                 // [B][128][N]
{
    __shared__ __align__(16) float accs[32 * 132];   // [q 32][c pad132]
    __shared__ float l_s[4 * 2 * 32];                // [w][half][q]

    int tid = threadIdx.x;
    int w = tid >> 6, lane = tid & 63;
    int q32 = lane & 31, half = lane >> 5;
    int b = blockIdx.x >> 7;                  // 128 q-groups of 32 per batch
    int i0 = (blockIdx.x & 127) * 32;
    f32x16 zf16;
#pragma unroll
    for (int r = 0; r < 16; r++) zf16[r] = 0.f;

    // Q B-frag (32x32x16): B[k=half*8+j][n=q32]
    bf16x8 qa = *(const bf16x8*)(qTb + ((size_t)(b * NN + i0 + q32)) * DQ + half * 8);

    f32x16 acc[4];                            // O^T[c][q]: c = g*32+(reg&3)+8*(reg>>2)+4*half
#pragma unroll
    for (int g = 0; g < 4; g++) acc[g] = zf16;
    float l = 0.f;

    const unsigned short* vtile = vB + ((size_t)(b * 64 + w * 16)) * 8192;
    const unsigned short* kbase = kTb + ((size_t)(b * NN + w * 16 * 64)) * DQ;

    // prefetch tile 0: K A-frags (A[m=key=q32][k=half*8+j]) + 16 V A-frags
    bf16x8 kb[2], vb[16];
#pragma unroll
    for (int mg = 0; mg < 2; mg++)
        kb[mg] = *(const bf16x8*)(kbase + (size_t)(mg * 32 + q32) * DQ + half * 8);
#pragma unroll
    for (int i = 0; i < 16; i++)
        vb[i] = *(const bf16x8*)(vtile + (size_t)i * 512 + (size_t)lane * 8);

    for (int t = 0; t < 16; t++) {
        // --- S^T = K·Q^T : two 32x32x16 (keys 0-31, 32-63) x 32 queries ---
        f32x16 s[2];
        s[0] = __builtin_amdgcn_mfma_f32_32x32x16_bf16(kb[0], qa, zf16, 0, 0, 0);
        s[1] = __builtin_amdgcn_mfma_f32_32x32x16_bf16(kb[1], qa, zf16, 0, 0, 0);
        const unsigned short* ktn = kbase + (size_t)(((t + 1) & 15) * 64) * DQ;
#pragma unroll
        for (int mg = 0; mg < 2; mg++)
            kb[mg] = *(const bf16x8*)(ktn + (size_t)(mg * 32 + q32) * DQ + half * 8);

        const unsigned short* vtn = vtile + ((t < 15) ? 8192 : 0);
        // --- per 16-key chunk: exp -> in-register B-frag -> 4 PV MFMAs ---
#pragma unroll
        for (int u = 0; u < 4; u++) {
            const int mg = u >> 1, h8 = (u & 1) * 8;
            // lane (q,half) holds keys-in-chunk {0..3}+4h (p0-3), {8..11}+4h (p4-7)
            float p0 = __expf(s[mg][h8 + 0]);
            float p1 = __expf(s[mg][h8 + 1]);
            float p2 = __expf(s[mg][h8 + 2]);
            float p3 = __expf(s[mg][h8 + 3]);
            float p4 = __expf(s[mg][h8 + 4]);
            float p5 = __expf(s[mg][h8 + 5]);
            float p6 = __expf(s[mg][h8 + 6]);
            float p7 = __expf(s[mg][h8 + 7]);
            l += ((p0 + p1) + (p2 + p3)) + ((p4 + p5) + (p6 + p7));
            unsigned int A0 = pk_trunc(p0, p1), A1 = pk_trunc(p2, p3);
            unsigned int A2 = pk_trunc(p4, p5), A3 = pk_trunc(p6, p7);
            // B-frag (B[k=8*half+j][n=q]) dwords:
            //  half0 needs [A0.own, A1.own, A0.from+32, A1.from+32]
            //  half1 needs [A2.from-32, A3.from-32, A2.own, A3.own]
            // swap(D,S): D.hi <-> S.lo  =>  D=A0,S=A2: A0={A0.lo|A2.lo},
            // A2={A0.hi|A2.hi}  (exactly word0/word2)
            asm("v_permlane32_swap_b32 %0, %1" : "+v"(A0), "+v"(A2));
            asm("v_permlane32_swap_b32 %0, %1" : "+v"(A1), "+v"(A3));
            u32x4 pbw = { A0, A1, A2, A3 };
            bf16x8 pb = __builtin_bit_cast(bf16x8, pbw);
#pragma unroll
            for (int g = 0; g < 4; g++)
                acc[g] = __builtin_amdgcn_mfma_f32_32x32x16_bf16(vb[g * 4 + u], pb, acc[g], 0, 0, 0);
            // prefetch this chunk's V frags for the next tile (consumed next t)
#pragma unroll
            for (int g = 0; g < 4; g++)
                vb[g * 4 + u] = *(const bf16x8*)(vtn + (size_t)(g * 4 + u) * 512 + (size_t)lane * 8);
        }
        vtile = vtn;
    }

    // --- cross-wave merge, single [q][c] buffer, 4 serialized rounds ---
    l_s[(w * 2 + half) * 32 + q32] = l;
    for (int ww = 0; ww < 4; ww++) {
        if (w == ww) {
#pragma unroll
            for (int g = 0; g < 4; g++)
#pragma unroll
                for (int r = 0; r < 4; r++) {
                    // acc[g][4r+i] -> c = g*32 + 8r + 4*half + i
                    float* p = accs + q32 * 132 + g * 32 + r * 8 + half * 4;
                    f32x4 v4 = { acc[g][r*4+0], acc[g][r*4+1], acc[g][r*4+2], acc[g][r*4+3] };
                    if (ww == 0) *(f32x4*)p = v4;
                    else { f32x4 o = *(const f32x4*)p; *(f32x4*)p = o + v4; }
                }
        }
        __syncthreads();
    }

    // --- epilogue: 256 threads, q = tid&31, 16 channels each ---
    float gam = gamma[0];
    int q = tid & 31, cg = tid >> 5;
    float L = 0.f;
#pragma unroll
    for (int u = 0; u < 8; u++) L += l_s[u * 32 + q];
    float linv = 1.f / L;
#pragma unroll
    for (int cc = 0; cc < 16; cc++) {
        int c = cg * 16 + cc;
        size_t gi = ((size_t)(b * CV + c)) * NN + i0 + q;
        out[gi] = gam * accs[q * 132 + c] * linv + xh[gi];
    }
}

extern "C" void kernel_launch(void* const* d_in, const int* in_sizes, int n_in,
                              void* d_out, int out_size, void* d_ws, size_t ws_size,
                              hipStream_t stream)
{
    (void)in_sizes; (void)n_in; (void)out_size; (void)ws_size;
    const float* x  = (const float*)d_in[0];
    const float* xh = (const float*)d_in[1];
    const float* Wq = (const float*)d_in[2];
    const float* bq = (const float*)d_in[3];
    const float* Wk = (const float*)d_in[4];
    const float* bk = (const float*)d_in[5];
    const float* Wv = (const float*)d_in[6];
    const float* bv = (const float*)d_in[7];
    const float* gm = (const float*)d_in[8];
    float* out = (float*)d_out;

    char* ws = (char*)d_ws;
    unsigned short* qTb = (unsigned short*)ws;                      // 512 KB
    unsigned short* kTb = (unsigned short*)(ws + (512 << 10));      // 512 KB
    unsigned short* vB  = (unsigned short*)(ws + (1 << 20));        // 4 MB

    proj<<<576, 256, 0, stream>>>(x, Wq, bq, Wk, bk, xh, Wv, bv, qTb, kTb, vB);
    flash_mfma<<<BB * 128, 256, 0, stream>>>(qTb, kTb, vB, xh, gm, out);
}